// Round 2
// baseline (94.468 us; speedup 1.0000x reference)
//
#include <hip/hip_runtime.h>

// LateralEI: out = GAIN * rownorm(K) @ h, K = 0.8*exp(-d2/0.72) - exp(-d2/2.88)
// z: [8192][2] f32, h: [8192][128] f32, out: [8192][128] f32
//
// R8 resubmit (R1 bench was an infra failure: "container failed twice", no
// kernel signal). Theory unchanged:
// R8: arithmetic-intensity fix. R4 (2048 waves), R6 (2048), R7 (4096) all
// landed ~same main-kernel time => per-CU THROUGHPUT cap, not latency
// (occupancy doubling was a no-op). Top per-CU pipe is LDS: 14 ds_read_b128
// per wave-iter (6 z-broadcast + 8 B-frag) feeding only 16 MFMAs.
// R8 runs 64 rows/wave (4 accumulator row-sets): the SAME 14 LDS reads feed
// 32 MFMAs -> per-CU b128 count halves (3584 -> 1792). acc = 128 VGPR so
// launch_bounds(256,2); grid 512 (NRT=32 x NKS=16) = 2 blocks/CU, 2048 waves.
// Ring discipline identical to R7 (depth-2, vmcnt(2)+bar, bar2 WAR):
//   produce(it+1) | w-compute(it) x4 rows | vmcnt(2)+bar1 | consume(it) | bar2
// Loop vmem = ONLY the 2 produce ops/wave -> vmcnt(2) deterministic.

typedef float f32x4 __attribute__((ext_vector_type(4)));
typedef float f32x2 __attribute__((ext_vector_type(2)));
typedef short s16x8 __attribute__((ext_vector_type(8)));
typedef unsigned int u32x4 __attribute__((ext_vector_type(4)));

#define NPTS 8192
#define DH 128
#define A_I (-0.5009357781f)  // -log2(e)/(2*1.2^2); A_E = 4*A_I
#define GAIN_C 0.05f

#define NKS 16      // cross-block K-slices (512 k each)
#define KSL 512     // k per slice
#define NITER 16    // 512 / 32
#define NRT 32      // row-tiles (256 rows each: 4 waves x 64 rows)

// ---------- pre-pass: h [8192][128] f32 -> hTf fragment-major bf16 (R4-verified) ----------
__global__ __launch_bounds__(256) void h_to_hTf(
    const float* __restrict__ h, unsigned short* __restrict__ hTf) {
  __shared__ unsigned int tileW[DH * 17];  // [n][kp], kp = k-pair 0..15
  const int t = threadIdx.x;
  const int k5 = blockIdx.x;
  const int n = t & 127;
  const int g = t >> 7;  // 0..1
#pragma unroll
  for (int p = 0; p < 8; ++p) {
    const int kp = g * 8 + p;
    unsigned int a = __float_as_uint(h[(k5 * 32 + 2 * kp) * DH + n]);
    unsigned int b = __float_as_uint(h[(k5 * 32 + 2 * kp + 1) * DH + n]);
    a = (a + 0x7fffu + ((a >> 16) & 1u)) >> 16;          // RNE low half
    b = (b + 0x7fffu + ((b >> 16) & 1u)) & 0xffff0000u;  // RNE high half
    tileW[n * 17 + kp] = a | b;
  }
  __syncthreads();
#pragma unroll
  for (int it = 0; it < 2; ++it) {
    const int u = t + it * 256;
    const int cf = u >> 6;
    const int lane = u & 63;
    const int nf = lane & 15;
    const int q = lane >> 4;
    const int n2 = cf * 16 + nf;
    u32x4 val;
#pragma unroll
    for (int i = 0; i < 4; ++i) val[i] = tileW[n2 * 17 + q * 4 + i];
    *(u32x4*)(hTf + k5 * 4096 + u * 8) = val;
  }
}

// stage one 8KB B-tile into a ring slot: 256 threads x 2 x 16B (2 instrs/wave)
__device__ __forceinline__ void produce_tile(const char* src, char* dst, int t) {
  __builtin_amdgcn_global_load_lds(
      (const __attribute__((address_space(1))) unsigned int*)(src + t * 16),
      (__attribute__((address_space(3))) unsigned int*)(dst + t * 16), 16, 0, 0);
  __builtin_amdgcn_global_load_lds(
      (const __attribute__((address_space(1))) unsigned int*)(src + 4096 + t * 16),
      (__attribute__((address_space(3))) unsigned int*)(dst + 4096 + t * 16), 16, 0, 0);
}

// ---------- main fused kernel ----------
__global__ __launch_bounds__(256, 2) void lateral_ei_main(
    const float* __restrict__ z, const unsigned short* __restrict__ hTf,
    unsigned short* __restrict__ partb, float* __restrict__ prs) {
  __shared__ __align__(16) unsigned short ring[2][4096];  // 2 x 8KB
  __shared__ __align__(16) float zxy[KSL * 2];            // 4KB (x,y) per k
  __shared__ __align__(16) float zaz[KSL];                // 2KB A_I*|z_k|^2

  const int t = threadIdx.x;
  const int lane = t & 63;
  const int w = t >> 6;  // wave 0..3
  const int rt = blockIdx.x & (NRT - 1);
  const int ks = blockIdx.x / NRT;  // 0..NKS-1
  const int i0 = rt * 256 + w * 64;
  const int nf = lane & 15;
  const int q = lane >> 4;
  const int k0 = ks * KSL;

  // zi constants for 4 row-sets: rows i0 + 16*r + nf
  float cA[4], cX[4], cY[4];
#pragma unroll
  for (int r = 0; r < 4; ++r) {
    const float zx = z[(i0 + 16 * r + nf) * 2];
    const float zy = z[(i0 + 16 * r + nf) * 2 + 1];
    cA[r] = A_I * (zx * zx + zy * zy);
    cX[r] = -2.f * A_I * zx;
    cY[r] = -2.f * A_I * zy;
  }

  const char* srcB = (const char*)hTf + (size_t)ks * (16 * 8192);
  char* ringB = (char*)&ring[0][0];

  // ---- preamble: stage slot 0; stage z/az slice (2 k per thread) ----
  produce_tile(srcB, ringB, t);
  {
    const int k2 = t * 2;
    const f32x4 p = *(const f32x4*)(z + (size_t)(k0 + k2) * 2);  // x0,y0,x1,y1
    *(f32x4*)(zxy + k2 * 2) = p;
    f32x2 az;
    az[0] = A_I * fmaf(p[1], p[1], p[0] * p[0]);
    az[1] = A_I * fmaf(p[3], p[3], p[2] * p[2]);
    *(f32x2*)(zaz + k2) = az;
  }
  __syncthreads();  // drains preamble vmem (incl. produce(0)) + LDS writes

  f32x4 acc[4][8];  // 128 VGPRs
#pragma unroll
  for (int r = 0; r < 4; ++r)
#pragma unroll
    for (int cf = 0; cf < 8; ++cf) acc[r][cf] = (f32x4){0.f, 0.f, 0.f, 0.f};
  float rsa[4] = {0.f, 0.f, 0.f, 0.f}, rsb[4] = {0.f, 0.f, 0.f, 0.f};

#pragma unroll 1
  for (int it = 0; it < NITER; ++it) {
    const int nit = (it + 1) & (NITER - 1);  // wrap: re-stages tile 0, never read

    // stage iter it+1 — the loop's ONLY vmem ops (2 instrs/wave)
    produce_tile(srcB + nit * 8192, ringB + ((it + 1) & 1) * 8192, t);

    // ---- w-production for iter it (z/az from LDS, quad-uniform broadcast)
    const float* zp_ = zxy + it * 64 + q * 16;
    const f32x4 zc0 = *(const f32x4*)(zp_ + 0);
    const f32x4 zc1 = *(const f32x4*)(zp_ + 4);
    const f32x4 zc2 = *(const f32x4*)(zp_ + 8);
    const f32x4 zc3 = *(const f32x4*)(zp_ + 12);
    const f32x4 az0 = *(const f32x4*)(zaz + it * 32 + q * 8);
    const f32x4 az1 = *(const f32x4*)(zaz + it * 32 + q * 8 + 4);

    union { unsigned int u[4]; s16x8 v; } af[4];
#pragma unroll
    for (int p = 0; p < 4; ++p) {  // j-pair (2p, 2p+1)
      const f32x4 zp = (p == 0) ? zc0 : (p == 1) ? zc1 : (p == 2) ? zc2 : zc3;
      const float azA = (p < 2) ? az0[2 * p] : az1[2 * p - 4];
      const float azB = (p < 2) ? az0[2 * p + 1] : az1[2 * p - 3];
#pragma unroll
      for (int r = 0; r < 4; ++r) {
        const float uA = fmaf(cX[r], zp[0], fmaf(cY[r], zp[1], cA[r] + azA));
        const float uB = fmaf(cX[r], zp[2], fmaf(cY[r], zp[3], cA[r] + azB));
        const float eA = __builtin_amdgcn_exp2f(uA);
        const float eB = __builtin_amdgcn_exp2f(uB);
        const float sA = eA * eA, sB = eB * eB;
        const float wA = fmaf(0.8f, sA * sA, -eA);  // e_E = e_I^4
        const float wB = fmaf(0.8f, sB * sB, -eB);
        rsa[r] += wA;
        rsb[r] += wB;
        af[r].u[p] = __builtin_amdgcn_perm(__float_as_uint(wB),
                                           __float_as_uint(wA), 0x07060302);
      }
    }

    // own produce(it) drained (only produce(it+1)'s 2 remain) -> bar1:
    // slot it fully landed for all 4 waves. Prefetch stays in flight.
    asm volatile("s_waitcnt vmcnt(2)\n\ts_barrier" ::: "memory");

    // ---- consume slot it: 8 B-frags via ds_read_b128, 32 MFMAs (4 row-sets)
    const char* rbl = ringB + (it & 1) * 8192 + lane * 16;
#pragma unroll
    for (int cf = 0; cf < 8; ++cf) {
      const s16x8 bfr = *(const s16x8*)(rbl + cf * 1024);
      acc[0][cf] = __builtin_amdgcn_mfma_f32_16x16x32_bf16(af[0].v, bfr, acc[0][cf], 0, 0, 0);
      acc[1][cf] = __builtin_amdgcn_mfma_f32_16x16x32_bf16(af[1].v, bfr, acc[1][cf], 0, 0, 0);
      acc[2][cf] = __builtin_amdgcn_mfma_f32_16x16x32_bf16(af[2].v, bfr, acc[2][cf], 0, 0, 0);
      acc[3][cf] = __builtin_amdgcn_mfma_f32_16x16x32_bf16(af[3].v, bfr, acc[3][cf], 0, 0, 0);
    }
    // bar2: depth-2 WAR — all waves' reads of slot (it&1) done before any
    // produce(it+2) (next body top) can touch it.
    asm volatile("s_barrier" ::: "memory");
  }

  // ---- rowsum: sum 4 quad-partials per row (lanes nf,nf+16,nf+32,nf+48)
#pragma unroll
  for (int r = 0; r < 4; ++r) {
    float rs = rsa[r] + rsb[r];
    rs += __shfl_xor(rs, 16);
    rs += __shfl_xor(rs, 32);
    if (lane < 16) prs[ks * NPTS + i0 + 16 * r + nf] = rs;
  }

  // ---- partial store, bf16 RNE (C/D layout: col=cf*16+nf, row=q*4+e)
  unsigned short* pb = partb + (size_t)ks * (NPTS * DH);
#pragma unroll
  for (int r = 0; r < 4; ++r)
#pragma unroll
    for (int cf = 0; cf < 8; ++cf)
#pragma unroll
      for (int e = 0; e < 4; ++e) {
        unsigned int u0 = __float_as_uint(acc[r][cf][e]);
        u0 = (u0 + 0x7fffu + ((u0 >> 16) & 1u)) >> 16;
        pb[(i0 + 16 * r + q * 4 + e) * DH + cf * 16 + nf] = (unsigned short)u0;
      }
}

// ---------- reduce NKS K-slice partials + normalize + scale ----------
__global__ __launch_bounds__(256) void reduce_scale(
    const unsigned short* __restrict__ partb, const float* __restrict__ prs,
    float* __restrict__ out) {
  const int gid = blockIdx.x * 256 + threadIdx.x;  // 8 cols each
  const int base = gid * 8;
  const int row = gid >> 4;
  float c[8] = {0.f, 0.f, 0.f, 0.f, 0.f, 0.f, 0.f, 0.f};
  float rsum = 0.f;
#pragma unroll
  for (int s = 0; s < NKS; ++s) {
    const u32x4 v = *(const u32x4*)(partb + (size_t)s * (NPTS * DH) + base);
#pragma unroll
    for (int i = 0; i < 4; ++i) {
      c[2 * i] += __uint_as_float(v[i] << 16);
      c[2 * i + 1] += __uint_as_float(v[i] & 0xffff0000u);
    }
    rsum += prs[s * NPTS + row];
  }
  const float scl = GAIN_C / (rsum + 1e-6f);
  f32x4 o0 = {c[0] * scl, c[1] * scl, c[2] * scl, c[3] * scl};
  f32x4 o1 = {c[4] * scl, c[5] * scl, c[6] * scl, c[7] * scl};
  *(f32x4*)(out + base) = o0;
  *(f32x4*)(out + base + 4) = o1;
}

extern "C" void kernel_launch(void* const* d_in, const int* in_sizes, int n_in,
                              void* d_out, int out_size, void* d_ws, size_t ws_size,
                              hipStream_t stream) {
  (void)in_sizes; (void)n_in; (void)out_size; (void)ws_size;
  const float* z = (const float*)d_in[0];
  const float* h = (const float*)d_in[1];
  float* out = (float*)d_out;
  unsigned short* hTf = (unsigned short*)d_ws;                          // 2 MiB
  unsigned short* partb = (unsigned short*)((char*)d_ws + (2u << 20));  // 32 MiB bf16
  float* prs = (float*)((char*)d_ws + (34u << 20));                     // 512 KiB

  h_to_hTf<<<NPTS / 32, 256, 0, stream>>>(h, hTf);
  lateral_ei_main<<<NRT * NKS, 256, 0, stream>>>(z, hTf, partb, prs);
  reduce_scale<<<(NPTS * DH / 8) / 256, 256, 0, stream>>>(partb, prs, out);
}